// Round 1
// baseline (1945.812 us; speedup 1.0000x reference)
//
#include <hip/hip_runtime.h>
#include <math.h>

// LSTM: B=64, T=2048, I=200, H=100. Output h_T [64,100] fp32.
// Plan:
//   prep_kernel : transpose W_ih -> Wt[200][512] (g padded to 512, zeros), bias = b_ih+b_hh (padded)
//   xproj_kernel: xg[b, t, g] = x[b,t,:]. Wt[:,g] + bias[g]   (fp32 tiled GEMM)
//   lstm_kernel : 64 WGs (one per batch), W_hh in VGPRs, h in LDS, 2048 sequential steps
// T is processed in chunks sized to fit xg in d_ws; h/c state persists in d_ws between chunks.

#define T_TOTAL 2048
#define B_SZ 64
#define IN_SZ 200
#define H_SZ 100
#define GP 512  // padded gate dim (4*H=400 -> 512)

__device__ __forceinline__ float sigf(float x) {
    return __builtin_amdgcn_rcpf(1.f + __expf(-x));
}
__device__ __forceinline__ float tanhf_fast(float x) {
    x = fminf(10.f, fmaxf(-10.f, x));
    float e = __expf(2.f * x);
    return (e - 1.f) * __builtin_amdgcn_rcpf(e + 1.f);
}

// ---------------- prep: Wt[k][g] = W_ih[g][k] (padded), bias[g] = b_ih[g]+b_hh[g] ----------------
__global__ void prep_kernel(const float* __restrict__ W_ih,
                            const float* __restrict__ b_ih,
                            const float* __restrict__ b_hh,
                            float* __restrict__ Wt,
                            float* __restrict__ bias) {
    int idx = blockIdx.x * 256 + threadIdx.x;
    if (idx < IN_SZ * GP) {
        int k = idx >> 9;        // /512
        int g = idx & (GP - 1);
        Wt[idx] = (g < 400) ? W_ih[g * IN_SZ + k] : 0.f;
    }
    if (idx < GP) bias[idx] = (idx < 400) ? (b_ih[idx] + b_hh[idx]) : 0.f;
}

// ---------------- input projection GEMM ----------------
// Block tile: 64 t-rows x 128 gates, K chunked by 50. 256 threads, thread tile 4t x 8g.
// Thread (tt = tid/16 in [0,16), gt = tid%16): t rows tt*4..+3 ; gates gbase + {gt*4..+3, 64+gt*4..+3}
__global__ __launch_bounds__(256, 4) void xproj_kernel(
    const float* __restrict__ x, const float* __restrict__ Wt,
    const float* __restrict__ bias, float* __restrict__ xg,
    int t0, int Tlen) {
    __shared__ __align__(16) float xTc[50][68];   // [k_local][t] transposed, padded
    __shared__ __align__(16) float4 LW[50][32];   // [k_local][g/4] for this 128-gate block

    const int tid = threadIdx.x;
    const int gblk = blockIdx.x;              // 0..3 -> gates gblk*128..+127
    const int tbase = t0 + blockIdx.y * 64;
    const int b = blockIdx.z;
    const int gt = tid & 15;
    const int tt = tid >> 4;

    float4 acc0[4], acc1[4];
#pragma unroll
    for (int r = 0; r < 4; ++r) {
        acc0[r] = make_float4(0.f, 0.f, 0.f, 0.f);
        acc1[r] = make_float4(0.f, 0.f, 0.f, 0.f);
    }

    const float2* x2 = (const float2*)x;
    const float4* Wt4 = (const float4*)Wt;

    for (int kc = 0; kc < 4; ++kc) {
        // stage x chunk, transposed: 64 rows x 50 k  (as 25 float2 per row)
        for (int idx = tid; idx < 64 * 25; idx += 256) {
            int row = idx / 25, c2 = idx % 25;
            float2 v = x2[(size_t)(b * T_TOTAL + tbase + row) * (IN_SZ / 2) + kc * 25 + c2];
            xTc[c2 * 2][row] = v.x;
            xTc[c2 * 2 + 1][row] = v.y;
        }
        // stage W chunk: 50 k x 32 float4 (=128 gates)
        for (int idx = tid; idx < 50 * 32; idx += 256) {
            int k = idx >> 5, c = idx & 31;
            LW[k][c] = Wt4[(size_t)(kc * 50 + k) * (GP / 4) + gblk * 32 + c];
        }
        __syncthreads();

#pragma unroll 5
        for (int k = 0; k < 50; ++k) {
            float4 xv = *(const float4*)&xTc[k][tt * 4];
            float4 w0 = LW[k][gt];
            float4 w1 = LW[k][16 + gt];
            float xa[4] = {xv.x, xv.y, xv.z, xv.w};
#pragma unroll
            for (int tr = 0; tr < 4; ++tr) {
                acc0[tr].x += xa[tr] * w0.x; acc0[tr].y += xa[tr] * w0.y;
                acc0[tr].z += xa[tr] * w0.z; acc0[tr].w += xa[tr] * w0.w;
                acc1[tr].x += xa[tr] * w1.x; acc1[tr].y += xa[tr] * w1.y;
                acc1[tr].z += xa[tr] * w1.z; acc1[tr].w += xa[tr] * w1.w;
            }
        }
        __syncthreads();
    }

    const float4* bias4 = (const float4*)bias;
    float4 b0 = bias4[gblk * 32 + gt];
    float4 b1 = bias4[gblk * 32 + 16 + gt];
    float4* o4 = (float4*)xg;
#pragma unroll
    for (int tr = 0; tr < 4; ++tr) {
        int trow = (tbase - t0) + tt * 4 + tr;  // chunk-local t
        size_t o = (size_t)(b * Tlen + trow) * (GP / 4) + gblk * 32;
        float4 v0 = make_float4(acc0[tr].x + b0.x, acc0[tr].y + b0.y, acc0[tr].z + b0.z, acc0[tr].w + b0.w);
        float4 v1 = make_float4(acc1[tr].x + b1.x, acc1[tr].y + b1.y, acc1[tr].z + b1.z, acc1[tr].w + b1.w);
        o4[o + gt] = v0;
        o4[o + 16 + gt] = v1;
    }
}

// ---------------- recurrence: one WG per batch ----------------
// 256 threads. Threads 0..199 each own gates 2t, 2t+1 with W_hh rows in VGPRs (50 float4).
// h[100] broadcast from LDS; gates staged in LDS; threads 0..99 do elementwise + c,h update.
__global__ __launch_bounds__(256, 1) void lstm_kernel(
    const float* __restrict__ xg, const float* __restrict__ Whh,
    float* __restrict__ hstate, float* __restrict__ cstate,
    float* __restrict__ out, int Tlen, int first, int last) {
    __shared__ __align__(16) float4 hsh4[25];  // h[100]
    __shared__ float gsh[400];

    const int b = blockIdx.x;
    const int tid = threadIdx.x;

    float4 wA[25], wB[25];
    if (tid < 200) {
        const float4* W4 = (const float4*)Whh;  // row = 100 floats = 25 float4
#pragma unroll
        for (int m = 0; m < 25; ++m) {
            wA[m] = W4[(size_t)(2 * tid) * 25 + m];
            wB[m] = W4[(size_t)(2 * tid + 1) * 25 + m];
        }
    }

    float c = 0.f;
    if (tid < 100) {
        c = first ? 0.f : cstate[b * H_SZ + tid];
        ((float*)hsh4)[tid] = first ? 0.f : hstate[b * H_SZ + tid];
    }
    __syncthreads();

    const float2* xg2 = (const float2*)xg;
    const size_t base = (size_t)b * Tlen * (GP / 2);

    float2 xv = make_float2(0.f, 0.f);
    if (tid < 200) xv = xg2[base + tid];

    for (int tl = 0; tl < Tlen; ++tl) {
        float2 xnext = xv;
        if (tid < 200 && (tl + 1) < Tlen) xnext = xg2[base + (size_t)(tl + 1) * (GP / 2) + tid];

        if (tid < 200) {
            float sAx = 0.f, sAy = 0.f, sAz = 0.f, sAw = 0.f;
            float sBx = 0.f, sBy = 0.f, sBz = 0.f, sBw = 0.f;
#pragma unroll
            for (int m = 0; m < 25; ++m) {
                float4 hv = hsh4[m];
                sAx += hv.x * wA[m].x; sAy += hv.y * wA[m].y;
                sAz += hv.z * wA[m].z; sAw += hv.w * wA[m].w;
                sBx += hv.x * wB[m].x; sBy += hv.y * wB[m].y;
                sBz += hv.z * wB[m].z; sBw += hv.w * wB[m].w;
            }
            gsh[2 * tid]     = xv.x + ((sAx + sAy) + (sAz + sAw));
            gsh[2 * tid + 1] = xv.y + ((sBx + sBy) + (sBz + sBw));
        }
        __syncthreads();

        if (tid < 100) {
            float gi = gsh[tid], gf = gsh[100 + tid], gg = gsh[200 + tid], go = gsh[300 + tid];
            float i = sigf(gi);
            float f = sigf(gf);
            float g = tanhf_fast(gg);
            float o = sigf(go);
            c = f * c + i * g;
            float h = o * tanhf_fast(c);
            ((float*)hsh4)[tid] = h;
        }
        __syncthreads();
        xv = xnext;
    }

    if (tid < 100) {
        float h = ((float*)hsh4)[tid];
        hstate[b * H_SZ + tid] = h;
        cstate[b * H_SZ + tid] = c;
        if (last) out[b * H_SZ + tid] = h;
    }
}

// ---------------- host ----------------
extern "C" void kernel_launch(void* const* d_in, const int* in_sizes, int n_in,
                              void* d_out, int out_size, void* d_ws, size_t ws_size,
                              hipStream_t stream) {
    const float* x    = (const float*)d_in[0];
    const float* W_ih = (const float*)d_in[1];
    const float* W_hh = (const float*)d_in[2];
    const float* b_ih = (const float*)d_in[3];
    const float* b_hh = (const float*)d_in[4];
    float* out = (float*)d_out;

    char* ws = (char*)d_ws;
    // layout: Wt (200*512*4=409600) | bias (512*4=2048) | hstate (25600) | cstate (25600) | xg chunk
    float* Wt     = (float*)(ws);
    float* bias   = (float*)(ws + 409600);
    float* hstate = (float*)(ws + 411648);
    float* cstate = (float*)(ws + 437248);
    float* xgbuf  = (float*)(ws + 462848);

    size_t cap = (ws_size > 462848) ? (ws_size - 462848) : 0;
    long long tcmax = (long long)(cap / ((size_t)B_SZ * GP * 4));  // per-chunk t capacity
    int Tc = (int)((tcmax / 64) * 64);
    if (Tc > T_TOTAL) Tc = T_TOTAL;
    if (Tc < 64) Tc = 64;  // assume ws >= ~9MB

    prep_kernel<<<400, 256, 0, stream>>>(W_ih, b_ih, b_hh, Wt, bias);

    for (int t0 = 0; t0 < T_TOTAL; t0 += Tc) {
        int Tlen = T_TOTAL - t0;
        if (Tlen > Tc) Tlen = Tc;
        xproj_kernel<<<dim3(4, Tlen / 64, B_SZ), 256, 0, stream>>>(x, Wt, bias, xgbuf, t0, Tlen);
        lstm_kernel<<<B_SZ, 256, 0, stream>>>(xgbuf, W_hh, hstate, cstate, out,
                                              Tlen, t0 == 0 ? 1 : 0,
                                              (t0 + Tlen) == T_TOTAL ? 1 : 0);
    }
}

// Round 2
// 1814.667 us; speedup vs baseline: 1.0723x; 1.0723x over previous
//
#include <hip/hip_runtime.h>
#include <math.h>

// LSTM: B=64, T=2048, I=200, H=100. Output h_T [64,100] fp32.
//   prep_kernel : transpose W_ih -> Wt[200][512] (g padded), bias = b_ih+b_hh
//   xproj_kernel: xg[b,t,g] = x[b,t,:].Wt[:,g] + bias[g]   (fp32 tiled GEMM)
//   lstm_kernel : 64 WGs (one per batch), 448 thr, one gate/thread, W_hh rows in VGPRs,
//                 quad-DPP gate exchange, double-buffered h in LDS, ONE barrier/step.

#define T_TOTAL 2048
#define B_SZ 64
#define IN_SZ 200
#define H_SZ 100
#define GP 512  // padded gate dim (4*H=400 -> 512)

typedef float v2f __attribute__((ext_vector_type(2)));

__device__ __forceinline__ float sigf(float x) {
    return __builtin_amdgcn_rcpf(1.f + __expf(-x));
}
__device__ __forceinline__ float tanhf_fast(float x) {
    x = fminf(10.f, fmaxf(-10.f, x));
    float e = __expf(2.f * x);
    return (e - 1.f) * __builtin_amdgcn_rcpf(e + 1.f);
}

// broadcast lane (ctrl/0x55) of each DPP quad to all 4 lanes of the quad
#define QBCAST(x, ctrl) \
    __int_as_float(__builtin_amdgcn_mov_dpp(__float_as_int(x), ctrl, 0xF, 0xF, true))

// ---------------- prep ----------------
__global__ void prep_kernel(const float* __restrict__ W_ih,
                            const float* __restrict__ b_ih,
                            const float* __restrict__ b_hh,
                            float* __restrict__ Wt,
                            float* __restrict__ bias) {
    int idx = blockIdx.x * 256 + threadIdx.x;
    if (idx < IN_SZ * GP) {
        int k = idx >> 9;
        int g = idx & (GP - 1);
        Wt[idx] = (g < 400) ? W_ih[g * IN_SZ + k] : 0.f;
    }
    if (idx < GP) bias[idx] = (idx < 400) ? (b_ih[idx] + b_hh[idx]) : 0.f;
}

// ---------------- input projection GEMM (unchanged from R1) ----------------
__global__ __launch_bounds__(256, 4) void xproj_kernel(
    const float* __restrict__ x, const float* __restrict__ Wt,
    const float* __restrict__ bias, float* __restrict__ xg,
    int t0, int Tlen) {
    __shared__ __align__(16) float xTc[50][68];
    __shared__ __align__(16) float4 LW[50][32];

    const int tid = threadIdx.x;
    const int gblk = blockIdx.x;
    const int tbase = t0 + blockIdx.y * 64;
    const int b = blockIdx.z;
    const int gt = tid & 15;
    const int tt = tid >> 4;

    float4 acc0[4], acc1[4];
#pragma unroll
    for (int r = 0; r < 4; ++r) {
        acc0[r] = make_float4(0.f, 0.f, 0.f, 0.f);
        acc1[r] = make_float4(0.f, 0.f, 0.f, 0.f);
    }

    const float2* x2 = (const float2*)x;
    const float4* Wt4 = (const float4*)Wt;

    for (int kc = 0; kc < 4; ++kc) {
        for (int idx = tid; idx < 64 * 25; idx += 256) {
            int row = idx / 25, c2 = idx % 25;
            float2 v = x2[(size_t)(b * T_TOTAL + tbase + row) * (IN_SZ / 2) + kc * 25 + c2];
            xTc[c2 * 2][row] = v.x;
            xTc[c2 * 2 + 1][row] = v.y;
        }
        for (int idx = tid; idx < 50 * 32; idx += 256) {
            int k = idx >> 5, c = idx & 31;
            LW[k][c] = Wt4[(size_t)(kc * 50 + k) * (GP / 4) + gblk * 32 + c];
        }
        __syncthreads();

#pragma unroll 5
        for (int k = 0; k < 50; ++k) {
            float4 xv = *(const float4*)&xTc[k][tt * 4];
            float4 w0 = LW[k][gt];
            float4 w1 = LW[k][16 + gt];
            float xa[4] = {xv.x, xv.y, xv.z, xv.w};
#pragma unroll
            for (int tr = 0; tr < 4; ++tr) {
                acc0[tr].x += xa[tr] * w0.x; acc0[tr].y += xa[tr] * w0.y;
                acc0[tr].z += xa[tr] * w0.z; acc0[tr].w += xa[tr] * w0.w;
                acc1[tr].x += xa[tr] * w1.x; acc1[tr].y += xa[tr] * w1.y;
                acc1[tr].z += xa[tr] * w1.z; acc1[tr].w += xa[tr] * w1.w;
            }
        }
        __syncthreads();
    }

    const float4* bias4 = (const float4*)bias;
    float4 b0 = bias4[gblk * 32 + gt];
    float4 b1 = bias4[gblk * 32 + 16 + gt];
    float4* o4 = (float4*)xg;
#pragma unroll
    for (int tr = 0; tr < 4; ++tr) {
        int trow = (tbase - t0) + tt * 4 + tr;
        size_t o = (size_t)(b * Tlen + trow) * (GP / 4) + gblk * 32;
        float4 v0 = make_float4(acc0[tr].x + b0.x, acc0[tr].y + b0.y, acc0[tr].z + b0.z, acc0[tr].w + b0.w);
        float4 v1 = make_float4(acc1[tr].x + b1.x, acc1[tr].y + b1.y, acc1[tr].z + b1.z, acc1[tr].w + b1.w);
        o4[o + gt] = v0;
        o4[o + 16 + gt] = v1;
    }
}

// ---------------- recurrence: one WG (448 thr) per batch ----------------
// Thread 4q+s (q<100, s in 0..3) owns gate s*100+q -> W_hh row in 50 v2f VGPRs.
// Per step: dot(h,W_row) via v_pk_fma_f32; quad DPP broadcast gathers i,f,g,o;
// every lane updates c,h redundantly; s==0 lane writes h to the OTHER LDS buffer;
// one __syncthreads per step.
__global__ __launch_bounds__(448, 1) void lstm_kernel(
    const float* __restrict__ xg, const float* __restrict__ Whh,
    float* __restrict__ hstate, float* __restrict__ cstate,
    float* __restrict__ out, int Tlen, int first, int last) {
    __shared__ __align__(16) float4 hsh4[2][25];  // double-buffered h[100]
    float* hshf = (float*)hsh4;

    const int b = blockIdx.x;
    const int tid = threadIdx.x;
    const int q = tid >> 2;
    const int s = tid & 3;
    const bool active = (tid < 400);
    const int gate = s * H_SZ + q;

    v2f w01[25], w23[25];
    if (active) {
        const float4* W4 = (const float4*)Whh;  // row = 25 float4
#pragma unroll
        for (int m = 0; m < 25; ++m) {
            float4 wv = W4[(size_t)gate * 25 + m];
            w01[m].x = wv.x; w01[m].y = wv.y;
            w23[m].x = wv.z; w23[m].y = wv.w;
        }
    }

    float c = 0.f;
    if (active) c = first ? 0.f : cstate[b * H_SZ + q];
    if (tid < H_SZ) hshf[tid] = first ? 0.f : hstate[b * H_SZ + tid];
    __syncthreads();

    const size_t base = (size_t)b * Tlen * GP;
    float xv = active ? xg[base + gate] : 0.f;
    float hval = 0.f;

    for (int tl = 0; tl < Tlen; ++tl) {
        float xnext = xv;
        if (active && (tl + 1) < Tlen) xnext = xg[base + (size_t)(tl + 1) * GP + gate];

        if (active) {
            const float4* hb = hsh4[tl & 1];
            v2f a0; a0.x = 0.f; a0.y = 0.f;
            v2f a1; a1.x = 0.f; a1.y = 0.f;
#pragma unroll
            for (int m = 0; m < 25; ++m) {
                float4 hv = hb[m];
                v2f h0; h0.x = hv.x; h0.y = hv.y;
                v2f h1; h1.x = hv.z; h1.y = hv.w;
                asm("v_pk_fma_f32 %0, %1, %2, %0" : "+v"(a0) : "v"(h0), "v"(w01[m]));
                asm("v_pk_fma_f32 %0, %1, %2, %0" : "+v"(a1) : "v"(h1), "v"(w23[m]));
            }
            float dot = xv + ((a0.x + a0.y) + (a1.x + a1.y));
            float vi = QBCAST(dot, 0x00);  // lane 0 of quad = gate i
            float vf = QBCAST(dot, 0x55);  // lane 1 = f
            float vg = QBCAST(dot, 0xAA);  // lane 2 = g
            float vo = QBCAST(dot, 0xFF);  // lane 3 = o
            float ig = sigf(vi);
            float fg = sigf(vf);
            float gg = tanhf_fast(vg);
            float og = sigf(vo);
            c = fg * c + ig * gg;
            hval = og * tanhf_fast(c);
            if (s == 0) hshf[((tl & 1) ^ 1) * H_SZ + q] = hval;
        }
        __syncthreads();
        xv = xnext;
    }

    if (active && s == 0) {
        hstate[b * H_SZ + q] = hval;
        cstate[b * H_SZ + q] = c;
        if (last) out[b * H_SZ + q] = hval;
    }
}

// ---------------- host ----------------
extern "C" void kernel_launch(void* const* d_in, const int* in_sizes, int n_in,
                              void* d_out, int out_size, void* d_ws, size_t ws_size,
                              hipStream_t stream) {
    const float* x    = (const float*)d_in[0];
    const float* W_ih = (const float*)d_in[1];
    const float* W_hh = (const float*)d_in[2];
    const float* b_ih = (const float*)d_in[3];
    const float* b_hh = (const float*)d_in[4];
    float* out = (float*)d_out;

    char* ws = (char*)d_ws;
    float* Wt     = (float*)(ws);
    float* bias   = (float*)(ws + 409600);
    float* hstate = (float*)(ws + 411648);
    float* cstate = (float*)(ws + 437248);
    float* xgbuf  = (float*)(ws + 462848);

    size_t cap = (ws_size > 462848) ? (ws_size - 462848) : 0;
    long long tcmax = (long long)(cap / ((size_t)B_SZ * GP * 4));
    int Tc = (int)((tcmax / 64) * 64);
    if (Tc > T_TOTAL) Tc = T_TOTAL;
    if (Tc < 64) Tc = 64;

    prep_kernel<<<400, 256, 0, stream>>>(W_ih, b_ih, b_hh, Wt, bias);

    for (int t0 = 0; t0 < T_TOTAL; t0 += Tc) {
        int Tlen = T_TOTAL - t0;
        if (Tlen > Tc) Tlen = Tc;
        xproj_kernel<<<dim3(4, Tlen / 64, B_SZ), 256, 0, stream>>>(x, Wt, bias, xgbuf, t0, Tlen);
        lstm_kernel<<<B_SZ, 448, 0, stream>>>(xgbuf, W_hh, hstate, cstate, out,
                                              Tlen, t0 == 0 ? 1 : 0,
                                              (t0 + Tlen) == T_TOTAL ? 1 : 0);
    }
}

// Round 3
// 1704.273 us; speedup vs baseline: 1.1417x; 1.0648x over previous
//
#include <hip/hip_runtime.h>
#include <math.h>

// LSTM: B=64, T=2048, I=200, H=100. Output h_T [64,100] fp32.
//   prep_kernel : transpose W_ih -> Wt[200][512] (g padded), bias = b_ih+b_hh
//   xproj_kernel: xg[b,t,g] = x[b,t,:].Wt[:,g] + bias[g]  (fp32 GEMM, pk_fma packed)
//   lstm_kernel : 64 WGs (one per batch), 448 thr, one gate/thread, W_hh rows in VGPRs
//                 (amdgpu_waves_per_eu(1,2) so the allocator keeps them), activation
//                 BEFORE quad-DPP exchange, double-buffered h in LDS, ONE barrier/step.

#define T_TOTAL 2048
#define B_SZ 64
#define IN_SZ 200
#define H_SZ 100
#define GP 512  // padded gate dim (4*H=400 -> 512)

typedef float v2f __attribute__((ext_vector_type(2)));

__device__ __forceinline__ float sigf(float x) {
    return __builtin_amdgcn_rcpf(1.f + __expf(-x));
}

// broadcast lane (ctrl) of each DPP quad to all 4 lanes of the quad
#define QBCAST(x, ctrl) \
    __int_as_float(__builtin_amdgcn_mov_dpp(__float_as_int(x), ctrl, 0xF, 0xF, true))

// ---------------- prep ----------------
__global__ void prep_kernel(const float* __restrict__ W_ih,
                            const float* __restrict__ b_ih,
                            const float* __restrict__ b_hh,
                            float* __restrict__ Wt,
                            float* __restrict__ bias) {
    int idx = blockIdx.x * 256 + threadIdx.x;
    if (idx < IN_SZ * GP) {
        int k = idx >> 9;
        int g = idx & (GP - 1);
        Wt[idx] = (g < 400) ? W_ih[g * IN_SZ + k] : 0.f;
    }
    if (idx < GP) bias[idx] = (idx < 400) ? (b_ih[idx] + b_hh[idx]) : 0.f;
}

// ---------------- input projection GEMM (pk_fma packed) ----------------
__global__ __launch_bounds__(256, 4) void xproj_kernel(
    const float* __restrict__ x, const float* __restrict__ Wt,
    const float* __restrict__ bias, float* __restrict__ xg,
    int t0, int Tlen) {
    __shared__ __align__(16) float xTc[50][68];
    __shared__ __align__(16) float4 LW[50][32];

    const int tid = threadIdx.x;
    const int gblk = blockIdx.x;
    const int tbase = t0 + blockIdx.y * 64;
    const int b = blockIdx.z;
    const int gt = tid & 15;
    const int tt = tid >> 4;

    // acc[tr][0..1] = gates gt*4..+3 (two v2f halves), acc[tr][2..3] = gates 64+gt*4..+3
    v2f acc[4][4];
#pragma unroll
    for (int r = 0; r < 4; ++r)
#pragma unroll
        for (int h = 0; h < 4; ++h) { acc[r][h].x = 0.f; acc[r][h].y = 0.f; }

    const float2* x2 = (const float2*)x;
    const float4* Wt4 = (const float4*)Wt;

    for (int kc = 0; kc < 4; ++kc) {
        for (int idx = tid; idx < 64 * 25; idx += 256) {
            int row = idx / 25, c2 = idx % 25;
            float2 v = x2[(size_t)(b * T_TOTAL + tbase + row) * (IN_SZ / 2) + kc * 25 + c2];
            xTc[c2 * 2][row] = v.x;
            xTc[c2 * 2 + 1][row] = v.y;
        }
        for (int idx = tid; idx < 50 * 32; idx += 256) {
            int k = idx >> 5, c = idx & 31;
            LW[k][c] = Wt4[(size_t)(kc * 50 + k) * (GP / 4) + gblk * 32 + c];
        }
        __syncthreads();

#pragma unroll 5
        for (int k = 0; k < 50; ++k) {
            float4 xv = *(const float4*)&xTc[k][tt * 4];
            float4 w0 = LW[k][gt];
            float4 w1 = LW[k][16 + gt];
            v2f wv[4];
            wv[0].x = w0.x; wv[0].y = w0.y; wv[1].x = w0.z; wv[1].y = w0.w;
            wv[2].x = w1.x; wv[2].y = w1.y; wv[3].x = w1.z; wv[3].y = w1.w;
            float xa[4] = {xv.x, xv.y, xv.z, xv.w};
#pragma unroll
            for (int tr = 0; tr < 4; ++tr) {
                v2f xs; xs.x = xa[tr]; xs.y = xa[tr];
#pragma unroll
                for (int h = 0; h < 4; ++h)
                    acc[tr][h] = __builtin_elementwise_fma(xs, wv[h], acc[tr][h]);
            }
        }
        __syncthreads();
    }

    const float4* bias4 = (const float4*)bias;
    float4 b0 = bias4[gblk * 32 + gt];
    float4 b1 = bias4[gblk * 32 + 16 + gt];
    float4* o4 = (float4*)xg;
#pragma unroll
    for (int tr = 0; tr < 4; ++tr) {
        int trow = (tbase - t0) + tt * 4 + tr;
        size_t o = (size_t)(b * Tlen + trow) * (GP / 4) + gblk * 32;
        float4 v0 = make_float4(acc[tr][0].x + b0.x, acc[tr][0].y + b0.y,
                                acc[tr][1].x + b0.z, acc[tr][1].y + b0.w);
        float4 v1 = make_float4(acc[tr][2].x + b1.x, acc[tr][2].y + b1.y,
                                acc[tr][3].x + b1.z, acc[tr][3].y + b1.w);
        o4[o + gt] = v0;
        o4[o + 16 + gt] = v1;
    }
}

// ---------------- recurrence: one WG (448 thr) per batch ----------------
// Thread 4q+s (q<100, s in 0..3) owns gate s*100+q -> W_hh row in 50 v2f VGPRs.
// Per step: dot(h,W_row) via packed fma; activate OWN gate; quad DPP broadcast of the
// 4 activated gates; every lane updates c,h redundantly; s==0 writes h to other buffer;
// one __syncthreads per step.
__global__ __attribute__((amdgpu_flat_work_group_size(448, 448), amdgpu_waves_per_eu(1, 2)))
void lstm_kernel(
    const float* __restrict__ xg, const float* __restrict__ Whh,
    float* __restrict__ hstate, float* __restrict__ cstate,
    float* __restrict__ out, int Tlen, int first, int last) {
    __shared__ __align__(16) float4 hsh4[2][25];  // double-buffered h[100]
    float* hshf = (float*)hsh4;

    const int b = blockIdx.x;
    const int tid = threadIdx.x;
    const int q = tid >> 2;
    const int s = tid & 3;
    const bool active = (tid < 400);
    const int gate = s * H_SZ + q;

    // W_hh row of this lane's gate: 50 float2 = 100 VGPRs, kept resident.
    v2f w[50];
    if (active) {
        const v2f* W2 = (const v2f*)Whh;
#pragma unroll
        for (int m = 0; m < 50; ++m) w[m] = W2[(size_t)gate * 50 + m];
    }

    // activation selector: tanh(x) = 2*sigmoid(2x)-1 ; sigmoid as-is
    const float a_scale = (s == 2) ? 2.f : 1.f;
    const float a_mul   = (s == 2) ? 2.f : 1.f;
    const float a_add   = (s == 2) ? -1.f : 0.f;

    float c = 0.f;
    if (active) c = first ? 0.f : cstate[b * H_SZ + q];
    if (tid < H_SZ) hshf[tid] = first ? 0.f : hstate[b * H_SZ + tid];
    __syncthreads();

    const size_t base = (size_t)b * Tlen * GP;
    float xv = active ? xg[base + gate] : 0.f;
    float hval = 0.f;

    for (int tl = 0; tl < Tlen; ++tl) {
        float xnext = xv;
        if (active && (tl + 1) < Tlen) xnext = xg[base + (size_t)(tl + 1) * GP + gate];

        float dot;
        {
            const v2f* hb = (const v2f*)hsh4[tl & 1];
            v2f a0; a0.x = 0.f; a0.y = 0.f;
            v2f a1; a1.x = 0.f; a1.y = 0.f;
#pragma unroll
            for (int m = 0; m < 25; ++m) {
                a0 = __builtin_elementwise_fma(hb[2 * m],     w[2 * m],     a0);
                a1 = __builtin_elementwise_fma(hb[2 * m + 1], w[2 * m + 1], a1);
            }
            v2f asum = a0 + a1;
            dot = xv + (asum.x + asum.y);
        }
        // activate own gate, then exchange activated values within the quad
        float act = __builtin_fmaf(sigf(a_scale * dot), a_mul, a_add);
        float vi = QBCAST(act, 0x00);  // lane 0 of quad = i (sigmoid)
        float vf = QBCAST(act, 0x55);  // lane 1 = f (sigmoid)
        float vg = QBCAST(act, 0xAA);  // lane 2 = g (tanh)
        float vo = QBCAST(act, 0xFF);  // lane 3 = o (sigmoid)
        c = __builtin_fmaf(vf, c, vi * vg);
        float tc = __builtin_fmaf(sigf(2.f * c), 2.f, -1.f);  // tanh(c)
        hval = vo * tc;
        if (active && s == 0) hshf[((tl & 1) ^ 1) * H_SZ + q] = hval;
        __syncthreads();
        xv = xnext;
    }

    if (active && s == 0) {
        hstate[b * H_SZ + q] = hval;
        cstate[b * H_SZ + q] = c;
        if (last) out[b * H_SZ + q] = hval;
    }
}

// ---------------- host ----------------
extern "C" void kernel_launch(void* const* d_in, const int* in_sizes, int n_in,
                              void* d_out, int out_size, void* d_ws, size_t ws_size,
                              hipStream_t stream) {
    const float* x    = (const float*)d_in[0];
    const float* W_ih = (const float*)d_in[1];
    const float* W_hh = (const float*)d_in[2];
    const float* b_ih = (const float*)d_in[3];
    const float* b_hh = (const float*)d_in[4];
    float* out = (float*)d_out;

    char* ws = (char*)d_ws;
    float* Wt     = (float*)(ws);
    float* bias   = (float*)(ws + 409600);
    float* hstate = (float*)(ws + 411648);
    float* cstate = (float*)(ws + 437248);
    float* xgbuf  = (float*)(ws + 462848);

    size_t cap = (ws_size > 462848) ? (ws_size - 462848) : 0;
    long long tcmax = (long long)(cap / ((size_t)B_SZ * GP * 4));
    int Tc = (int)((tcmax / 64) * 64);
    if (Tc > T_TOTAL) Tc = T_TOTAL;
    if (Tc < 64) Tc = 64;

    prep_kernel<<<400, 256, 0, stream>>>(W_ih, b_ih, b_hh, Wt, bias);

    for (int t0 = 0; t0 < T_TOTAL; t0 += Tc) {
        int Tlen = T_TOTAL - t0;
        if (Tlen > Tc) Tlen = Tc;
        xproj_kernel<<<dim3(4, Tlen / 64, B_SZ), 256, 0, stream>>>(x, Wt, bias, xgbuf, t0, Tlen);
        lstm_kernel<<<B_SZ, 448, 0, stream>>>(xgbuf, W_hh, hstate, cstate, out,
                                              Tlen, t0 == 0 ? 1 : 0,
                                              (t0 + Tlen) == T_TOTAL ? 1 : 0);
    }
}